// Round 7
// baseline (283.332 us; speedup 1.0000x reference)
//
#include <hip/hip_runtime.h>
#include <hip/hip_bf16.h>
#include <stdint.h>
#include <stddef.h>

typedef __bf16 bf16_t;
typedef __bf16 bf16x4 __attribute__((ext_vector_type(4)));
typedef __bf16 bf16x8 __attribute__((ext_vector_type(8)));
typedef float  f32x4  __attribute__((ext_vector_type(4)));

static __device__ __forceinline__ f32x4 zero4() { return (f32x4){0.f, 0.f, 0.f, 0.f}; }

#define MFMA16(a, b, c) __builtin_amdgcn_mfma_f32_16x16x32_bf16((a), (b), (c), 0, 0, 0)

#define GLOAD_LDS16(gptr, lptr)                                                        \
  __builtin_amdgcn_global_load_lds((const __attribute__((address_space(1))) void*)(gptr), \
                                   (__attribute__((address_space(3))) void*)(lptr), 16, 0, 0)

// ---------------- cast x fp32 -> bf16, 8 elems/thread ----------------
__global__ __launch_bounds__(256) void k_cast(const float* __restrict__ in,
                                              bf16_t* __restrict__ out) {
  size_t i = (size_t)blockIdx.x * 256 + threadIdx.x;
  const float4* p = (const float4*)in;
  float4 a = p[i * 2 + 0];
  float4 b = p[i * 2 + 1];
  bf16x8 v;
  v[0] = (bf16_t)a.x; v[1] = (bf16_t)a.y; v[2] = (bf16_t)a.z; v[3] = (bf16_t)a.w;
  v[4] = (bf16_t)b.x; v[5] = (bf16_t)b.y; v[6] = (bf16_t)b.z; v[7] = (bf16_t)b.w;
  *(bf16x8*)(out + i * 8) = v;
}

// ------------- transpose-cast: in fp32 [R][C] -> out bf16 [C][R] -------------
__global__ __launch_bounds__(256) void k_tcast(const float* __restrict__ in,
                                               bf16_t* __restrict__ out,
                                               int R, int C) {
  __shared__ bf16_t tile[64][72];
  int c0 = blockIdx.x * 64, r0 = blockIdx.y * 64;
  int t = threadIdx.x;
  int r = t >> 2, cc = (t & 3) * 16;
  const float* src = in + (size_t)(r0 + r) * C + c0 + cc;
#pragma unroll
  for (int q = 0; q < 4; ++q) {
    float4 v = *(const float4*)(src + q * 4);
    tile[r][cc + q * 4 + 0] = (bf16_t)v.x;
    tile[r][cc + q * 4 + 1] = (bf16_t)v.y;
    tile[r][cc + q * 4 + 2] = (bf16_t)v.z;
    tile[r][cc + q * 4 + 3] = (bf16_t)v.w;
  }
  __syncthreads();
  int c = t >> 2, rr = (t & 3) * 16;
  bf16x8 o0, o1;
#pragma unroll
  for (int j = 0; j < 8; ++j) { o0[j] = tile[rr + j][c]; o1[j] = tile[rr + 8 + j][c]; }
  bf16_t* dst = out + (size_t)(c0 + c) * R + r0 + rr;
  *(bf16x8*)dst = o0;
  *(bf16x8*)(dst + 8) = o1;
}

// ---- fused QKV GEMM: qkv = xb @ wqkvT^T, epilogue scatters to qh/kh/vT ----
// qh[bh][2048][64]; kh[bh][2048][64] scaled by log2(e)/8; vT[bh*64+d][2048].
__global__ __launch_bounds__(256) void k_gemm_qkv(const bf16_t* __restrict__ A,
                                                  const bf16_t* __restrict__ BT,
                                                  bf16_t* __restrict__ qh,
                                                  bf16_t* __restrict__ kh,
                                                  bf16_t* __restrict__ vT) {
  constexpr int K = 1024;
  __shared__ bf16_t sA[128 * 32];
  __shared__ bf16_t sB[128 * 32];
  __shared__ bf16_t vtile[4][64][72];          // per-wave epilogue staging
  int tid = threadIdx.x;
  int wid = tid >> 6, lane = tid & 63;
  int cl = lane & 15, gp = lane >> 4;
  int nwg = gridDim.x * gridDim.y;
  int flat = blockIdx.y * gridDim.x + blockIdx.x;
  int cpx = nwg >> 3;
  int swzid = (flat & 7) * cpx + (flat >> 3);
  int brow = (swzid / gridDim.x) * 128, bcol = (swzid % gridDim.x) * 128;
  int wr = wid >> 1, wc = wid & 1;
  f32x4 acc[4][4];
#pragma unroll
  for (int i = 0; i < 4; ++i)
#pragma unroll
    for (int j = 0; j < 4; ++j) acc[i][j] = zero4();

  int srow = tid >> 2;
  int sk = (tid & 3) * 8;
  const bf16_t* gA = A + (size_t)(brow + srow) * K + sk;
  const bf16_t* gB = BT + (size_t)(bcol + srow) * K + sk;
  char* lA = (char*)sA + wid * 1024;
  char* lB = (char*)sB + wid * 1024;

  for (int k0 = 0; k0 < K; k0 += 32) {
    __syncthreads();
    GLOAD_LDS16(gA + k0, lA);
    GLOAD_LDS16(gA + (size_t)64 * K + k0, lA + 4096);
    GLOAD_LDS16(gB + k0, lB);
    GLOAD_LDS16(gB + (size_t)64 * K + k0, lB + 4096);
    __syncthreads();
    bf16x8 af[4], bfr[4];
#pragma unroll
    for (int i = 0; i < 4; ++i)
      af[i] = *(const bf16x8*)&sA[(wr * 64 + i * 16 + cl) * 32 + gp * 8];
#pragma unroll
    for (int j = 0; j < 4; ++j)
      bfr[j] = *(const bf16x8*)&sB[(wc * 64 + j * 16 + cl) * 32 + gp * 8];
#pragma unroll
    for (int i = 0; i < 4; ++i)
#pragma unroll
      for (int j = 0; j < 4; ++j)
        acc[i][j] = MFMA16(af[i], bfr[j], acc[i][j]);
  }

  // epilogue: this wave's 64-col span = exactly one head of one region
  int b_ = brow >> 11;                         // batch (2048 rows each)
  int t0 = (brow & 2047) + wr * 64;            // token offset of this wave
  int colbase = bcol + wc * 64;
  int region = colbase >> 10;                  // 0=Q 1=K 2=V
  int h_ = (colbase & 1023) >> 6;
  size_t bh_ = (size_t)(b_ * 16 + h_);
  bf16_t (*vt)[72] = vtile[wid];               // wave-private -> no barrier

  if (region < 2) {
    // stage [token][d] then vector-store one 128B token-row per lane
    float sc = (region == 0) ? 1.0f : 0.18033688011f;   // log2(e)/8 for K
#pragma unroll
    for (int i = 0; i < 4; ++i)
#pragma unroll
      for (int j = 0; j < 4; ++j)
#pragma unroll
        for (int e = 0; e < 4; ++e)
          vt[i * 16 + gp * 4 + e][j * 16 + cl] = (bf16_t)(acc[i][j][e] * sc);
    bf16_t* dst0 = (region == 0 ? qh : kh) + (bh_ * 2048 + t0 + lane) * 64;
    const bf16_t* src = &vt[lane][0];
#pragma unroll
    for (int q = 0; q < 64; q += 8)
      *(bf16x8*)(dst0 + q) = *(const bf16x8*)(src + q);
  } else {
    // stage transposed [d][token] then vector-store one token-run per lane
#pragma unroll
    for (int i = 0; i < 4; ++i)
#pragma unroll
      for (int j = 0; j < 4; ++j)
#pragma unroll
        for (int e = 0; e < 4; ++e)
          vt[j * 16 + cl][i * 16 + gp * 4 + e] = (bf16_t)acc[i][j][e];
    const bf16_t* src = &vt[lane][0];
    bf16_t* dst = vT + (bh_ * 64 + lane) * 2048 + t0;
#pragma unroll
    for (int tt = 0; tt < 64; tt += 8)
      *(bf16x8*)(dst + tt) = *(const bf16x8*)(src + tt);
  }
}

// ------- proj GEMM: C[M][N] = A[M][K] * BT[N][K]^T + bias (fp32 out) -------
__global__ __launch_bounds__(256) void k_gemm_proj(const bf16_t* __restrict__ A,
                                                   const bf16_t* __restrict__ BT,
                                                   float* __restrict__ Cout,
                                                   const float* __restrict__ bias,
                                                   int M, int N, int K) {
  __shared__ bf16_t sA[128 * 32];
  __shared__ bf16_t sB[128 * 32];
  __shared__ float ptile[4][16][68];           // per-wave epilogue staging
  int tid = threadIdx.x;
  int wid = tid >> 6, lane = tid & 63;
  int cl = lane & 15, gp = lane >> 4;
  int nwg = gridDim.x * gridDim.y;
  int flat = blockIdx.y * gridDim.x + blockIdx.x;
  int cpx = nwg >> 3;
  int swzid = (flat & 7) * cpx + (flat >> 3);
  int brow = (swzid / gridDim.x) * 128, bcol = (swzid % gridDim.x) * 128;
  int wr = wid >> 1, wc = wid & 1;
  f32x4 acc[4][4];
#pragma unroll
  for (int i = 0; i < 4; ++i)
#pragma unroll
    for (int j = 0; j < 4; ++j) acc[i][j] = zero4();

  int srow = tid >> 2;
  int sk = (tid & 3) * 8;
  const bf16_t* gA = A + (size_t)(brow + srow) * K + sk;
  const bf16_t* gB = BT + (size_t)(bcol + srow) * K + sk;
  char* lA = (char*)sA + wid * 1024;
  char* lB = (char*)sB + wid * 1024;

  for (int k0 = 0; k0 < K; k0 += 32) {
    __syncthreads();
    GLOAD_LDS16(gA + k0, lA);
    GLOAD_LDS16(gA + (size_t)64 * K + k0, lA + 4096);
    GLOAD_LDS16(gB + k0, lB);
    GLOAD_LDS16(gB + (size_t)64 * K + k0, lB + 4096);
    __syncthreads();
    bf16x8 af[4], bfr[4];
#pragma unroll
    for (int i = 0; i < 4; ++i)
      af[i] = *(const bf16x8*)&sA[(wr * 64 + i * 16 + cl) * 32 + gp * 8];
#pragma unroll
    for (int j = 0; j < 4; ++j)
      bfr[j] = *(const bf16x8*)&sB[(wc * 64 + j * 16 + cl) * 32 + gp * 8];
#pragma unroll
    for (int i = 0; i < 4; ++i)
#pragma unroll
      for (int j = 0; j < 4; ++j)
        acc[i][j] = MFMA16(af[i], bfr[j], acc[i][j]);
  }

  // epilogue: per i-chunk LDS repack -> float4 stores (bias hoisted)
  int r = lane & 15, q = lane >> 4;            // lane covers row r, col quarter q
  int colq = bcol + wc * 64 + q * 16;
  float4 bias4[4];
#pragma unroll
  for (int q2 = 0; q2 < 4; ++q2) bias4[q2] = *(const float4*)(bias + colq + q2 * 4);
  float (*pt)[68] = ptile[wid];
#pragma unroll
  for (int i = 0; i < 4; ++i) {
#pragma unroll
    for (int j = 0; j < 4; ++j)
#pragma unroll
      for (int e = 0; e < 4; ++e)
        pt[gp * 4 + e][j * 16 + cl] = acc[i][j][e];
    asm volatile("" ::: "memory");             // order writes vs reads (same wave)
    float* dst = Cout + (size_t)(brow + wr * 64 + i * 16 + r) * N + colq;
#pragma unroll
    for (int q2 = 0; q2 < 4; ++q2) {
      float4 v = *(const float4*)&pt[r][q * 16 + q2 * 4];
      v.x += bias4[q2].x; v.y += bias4[q2].y; v.z += bias4[q2].z; v.w += bias4[q2].w;
      *(float4*)(dst + q2 * 4) = v;
    }
    asm volatile("" ::: "memory");             // reads done before next chunk writes
  }
}

// ---------------- attention v6 (exp2 domain, lsum via ones-MFMA) ----------------
static __device__ __forceinline__ float max3f(float a, float b, float c) {
  return fmaxf(fmaxf(a, b), c);                // fuses to v_max3_f32
}

static __device__ __forceinline__ void pass16(const char* __restrict__ bK,
                                              const char* __restrict__ bV,
                                              char* __restrict__ Pw,
                                              const bf16x8& qa, const bf16x8& qb,
                                              const bf16x8& ones8,
                                              f32x4 (&o)[4], f32x4& ol, float& mrun,
                                              int kv0, int qw, int swz, int cl, int gp) {
  f32x4 s[4];
  __builtin_amdgcn_s_setprio(1);
#pragma unroll
  for (int jj = 0; jj < 4; ++jj) {
    const char* base = bK + (jj * 16 + cl) * 128;
    bf16x8 k0 = *(const bf16x8*)(base + ((gp * 16) ^ swz));
    bf16x8 k1 = *(const bf16x8*)(base + ((64 + gp * 16) ^ swz));
    f32x4 a = zero4();
    a = MFMA16(k0, qa, a);
    a = MFMA16(k1, qb, a);
    s[jj] = a;
  }
  __builtin_amdgcn_s_setprio(0);

  if (kv0 + 63 > qw) {                        // only the diagonal tile masks
    int thr = qw + cl - kv0 - gp * 4;         // elem (jj,e) masked iff jj*16+e > thr
#pragma unroll
    for (int jj = 0; jj < 4; ++jj)
#pragma unroll
      for (int e = 0; e < 4; ++e)
        if (jj * 16 + e > thr) s[jj][e] = -1e30f;
  }
  float m1 = max3f(s[0][0], s[0][1], s[0][2]);
  float m2 = max3f(s[0][3], s[1][0], s[1][1]);
  float m3 = max3f(s[1][2], s[1][3], s[2][0]);
  float m4 = max3f(s[2][1], s[2][2], s[2][3]);
  float m5 = max3f(s[3][0], s[3][1], s[3][2]);
  float pm = fmaxf(max3f(max3f(m1, m2, m3), m4, m5), s[3][3]);
  pm = fmaxf(pm, __shfl_xor(pm, 16));
  pm = fmaxf(pm, __shfl_xor(pm, 32));
  float mnew = mrun;
  if (!__all(pm <= mnew + 11.5f)) {           // defer-max (T13), log2 domain
    float mold = mnew;
    mnew = fmaxf(mold, pm);
    float aa = exp2f(mold - mnew);
    mrun = mnew;
#pragma unroll
    for (int e = 0; e < 4; ++e) {
      float ae = __shfl(aa, gp * 4 + e);
      ol[e] *= ae;
#pragma unroll
      for (int c = 0; c < 4; ++c) o[c][e] *= ae;
    }
  }
#pragma unroll
  for (int jj = 0; jj < 4; ++jj) {
    bf16x4 pw;
#pragma unroll
    for (int e = 0; e < 4; ++e) pw[e] = (bf16_t)exp2f(s[jj][e] - mnew);
    *(bf16x4*)(Pw + cl * 128 + ((jj * 32 + gp * 8) ^ swz)) = pw;
  }

  asm volatile("" ::: "memory");              // P writes before P reads (same wave)
  bf16x8 pa0 = *(const bf16x8*)(Pw + cl * 128 + ((gp * 16) ^ swz));
  bf16x8 pa1 = *(const bf16x8*)(Pw + cl * 128 + ((64 + gp * 16) ^ swz));

  __builtin_amdgcn_s_setprio(1);
  ol = MFMA16(pa0, ones8, ol);                // lsum on the idle MFMA pipe
  ol = MFMA16(pa1, ones8, ol);
#pragma unroll
  for (int c = 0; c < 4; ++c) {
    const char* base = bV + (c * 16 + cl) * 128;
    bf16x8 v0 = *(const bf16x8*)(base + ((gp * 16) ^ swz));
    bf16x8 v1 = *(const bf16x8*)(base + ((64 + gp * 16) ^ swz));
    o[c] = MFMA16(pa0, v0, o[c]);
    o[c] = MFMA16(pa1, v1, o[c]);
  }
  __builtin_amdgcn_s_setprio(0);
  asm volatile("" ::: "memory");              // pa/v reads done before P rewrite
}

// ---- attention: QBLK=64, paired q-tiles (jL, 31-jL), 4 blocks/CU ----
__global__ __launch_bounds__(256, 4) void k_attn6(const bf16_t* __restrict__ qh,
                                                  const bf16_t* __restrict__ kh,
                                                  const bf16_t* __restrict__ vT,
                                                  bf16_t* __restrict__ out) {
  __shared__ alignas(16) char sK[2][8192];     // [64 kv][128B d], XOR-swizzled
  __shared__ alignas(16) char sV[2][8192];     // [64 d][128B kv], XOR-swizzled
  __shared__ alignas(16) char sP[4][2048];     // per wave: 16q x 128B P buffer

  int n = blockIdx.x;
  int bh = ((n & 7) << 3) | ((n >> 3) & 7);    // same head group -> same XCD
  int pr = n >> 6;                             // 0..15
  int jL = pr, jH = 31 - pr;                   // paired q-tiles: uniform work
  int b = bh >> 4;
  int tid = threadIdx.x, wid = tid >> 6, lane = tid & 63;
  int cl = lane & 15, gp = lane >> 4;

  int qwL = jL * 64 + wid * 16;
  int qwH = jH * 64 + wid * 16;

  // Q fragments (B-operand) from compact qh: col=cl(q), k(d)=gp*8+e
  bf16x8 qL0, qL1, qH0, qH1;
  {
    const bf16_t* p = qh + ((size_t)bh * 2048 + qwL + cl) * 64 + gp * 8;
    qL0 = *(const bf16x8*)p; qL1 = *(const bf16x8*)(p + 32);
    p = qh + ((size_t)bh * 2048 + qwH + cl) * 64 + gp * 8;
    qH0 = *(const bf16x8*)p; qH1 = *(const bf16x8*)(p + 32);
  }
  bf16x8 ones8;
#pragma unroll
  for (int e = 0; e < 8; ++e) ones8[e] = (bf16_t)1.0f;

  int srow = tid >> 3;
  int swzcb = ((tid & 7) * 16) ^ ((srow & 7) << 4);
  const bf16_t* gK = kh + ((size_t)bh * 2048 + srow) * 64 + (swzcb >> 1);
  const bf16_t* gV = vT + ((size_t)(bh * 64) + srow) * 2048 + (swzcb >> 1);

  f32x4 oL[4], oH[4], olL = zero4(), olH = zero4();
#pragma unroll
  for (int c = 0; c < 4; ++c) { oL[c] = zero4(); oH[c] = zero4(); }
  float mrunL = -1e30f, mrunH = -1e30f;

  int swz = (cl & 7) << 4;
  int nt = jH + 1;                             // KV64 tiles (H's causal extent)
  char* Pw = sP[wid];

  {
    char* lK = sK[0] + wid * 1024;
    char* lV = sV[0] + wid * 1024;
    GLOAD_LDS16(gK, lK);
    GLOAD_LDS16(gK + 32 * 64, lK + 4096);
    GLOAD_LDS16(gV, lV);
    GLOAD_LDS16(gV + (size_t)32 * 2048, lV + 4096);
  }
  asm volatile("s_waitcnt vmcnt(0)");
  __syncthreads();

  for (int t = 0; t < nt; ++t) {
    int cur = t & 1;
    int kv0 = t * 64;
    if (t + 1 < nt) {
      int kv1 = kv0 + 64;
      char* lK = sK[cur ^ 1] + wid * 1024;
      char* lV = sV[cur ^ 1] + wid * 1024;
      GLOAD_LDS16(gK + (size_t)kv1 * 64, lK);
      GLOAD_LDS16(gK + (size_t)(kv1 + 32) * 64, lK + 4096);
      GLOAD_LDS16(gV + kv1, lV);
      GLOAD_LDS16(gV + kv1 + (size_t)32 * 2048, lV + 4096);
    }
    const char* bK = sK[cur];
    const char* bV = sV[cur];

    if (t <= jL)
      pass16(bK, bV, Pw, qL0, qL1, ones8, oL, olL, mrunL, kv0, qwL, swz, cl, gp);
    pass16(bK, bV, Pw, qH0, qH1, ones8, oH, olH, mrunH, kv0, qwH, swz, cl, gp);

    asm volatile("s_waitcnt vmcnt(0)");
    __syncthreads();
  }

  // epilogue: lsum already in acc-row domain (ol[e] = row gp*4+e) -> no shuffles
#pragma unroll
  for (int e = 0; e < 4; ++e) {
    float iL = 1.0f / olL[e];
    float iH = 1.0f / olH[e];
    int rL = qwL + gp * 4 + e;
    int rH = qwH + gp * 4 + e;
    int h = bh & 15;
#pragma unroll
    for (int c = 0; c < 4; ++c) {
      int col = h * 64 + c * 16 + cl;
      out[(size_t)(b * 2048 + rL) * 1024 + col] = (bf16_t)(oL[c][e] * iL);
      out[(size_t)(b * 2048 + rH) * 1024 + col] = (bf16_t)(oH[c][e] * iH);
    }
  }
}

// ---------------------------------------------------------------------------
extern "C" void kernel_launch(void* const* d_in, const int* in_sizes, int n_in,
                              void* d_out, int out_size, void* d_ws, size_t ws_size,
                              hipStream_t stream) {
  const float* x      = (const float*)d_in[0];
  const float* w_qkv  = (const float*)d_in[1];
  const float* w_proj = (const float*)d_in[2];
  const float* b_proj = (const float*)d_in[3];
  float* outp = (float*)d_out;

  char* ws = (char*)d_ws;
  bf16_t* xb     = (bf16_t*)(ws);                    // 16 MiB
  bf16_t* wqkvT  = (bf16_t*)(ws + (16u << 20));      // 6 MiB
  bf16_t* wprojT = (bf16_t*)(ws + (22u << 20));      // 2 MiB
  bf16_t* qh     = (bf16_t*)(ws + (24u << 20));      // 16 MiB
  bf16_t* kh     = (bf16_t*)(ws + (40u << 20));      // 16 MiB
  bf16_t* vT     = (bf16_t*)(ws + (56u << 20));      // 16 MiB
  bf16_t* aout   = (bf16_t*)(ws + (72u << 20));      // 16 MiB

  k_cast<<<dim3(8192 * 1024 / (256 * 8)), 256, 0, stream>>>(x, xb);
  k_tcast<<<dim3(3072 / 64, 1024 / 64), 256, 0, stream>>>(w_qkv, wqkvT, 1024, 3072);
  k_tcast<<<dim3(1024 / 64, 1024 / 64), 256, 0, stream>>>(w_proj, wprojT, 1024, 1024);
  k_gemm_qkv<<<dim3(3072 / 128, 8192 / 128), 256, 0, stream>>>(xb, wqkvT, qh, kh, vT);
  k_attn6<<<dim3(1024), 256, 0, stream>>>(qh, kh, vT, aout);
  k_gemm_proj<<<dim3(1024 / 128, 8192 / 128), 256, 0, stream>>>(
      aout, wprojT, outp, b_proj, 8192, 1024, 1024);
}

// Round 9
// 270.213 us; speedup vs baseline: 1.0486x; 1.0486x over previous
//
#include <hip/hip_runtime.h>
#include <hip/hip_bf16.h>
#include <stdint.h>
#include <stddef.h>

typedef __bf16 bf16_t;
typedef __bf16 bf16x4 __attribute__((ext_vector_type(4)));
typedef __bf16 bf16x8 __attribute__((ext_vector_type(8)));
typedef float  f32x4  __attribute__((ext_vector_type(4)));

static __device__ __forceinline__ f32x4 zero4() { return (f32x4){0.f, 0.f, 0.f, 0.f}; }

#define MFMA16(a, b, c) __builtin_amdgcn_mfma_f32_16x16x32_bf16((a), (b), (c), 0, 0, 0)

#define GLOAD_LDS16(gptr, lptr)                                                        \
  __builtin_amdgcn_global_load_lds((const __attribute__((address_space(1))) void*)(gptr), \
                                   (__attribute__((address_space(3))) void*)(lptr), 16, 0, 0)

// ---------------- cast x fp32 -> bf16, 8 elems/thread ----------------
__global__ __launch_bounds__(256) void k_cast(const float* __restrict__ in,
                                              bf16_t* __restrict__ out) {
  size_t i = (size_t)blockIdx.x * 256 + threadIdx.x;
  const float4* p = (const float4*)in;
  float4 a = p[i * 2 + 0];
  float4 b = p[i * 2 + 1];
  bf16x8 v;
  v[0] = (bf16_t)a.x; v[1] = (bf16_t)a.y; v[2] = (bf16_t)a.z; v[3] = (bf16_t)a.w;
  v[4] = (bf16_t)b.x; v[5] = (bf16_t)b.y; v[6] = (bf16_t)b.z; v[7] = (bf16_t)b.w;
  *(bf16x8*)(out + i * 8) = v;
}

// ------------- transpose-cast: in fp32 [R][C] -> out bf16 [C][R] -------------
__global__ __launch_bounds__(256) void k_tcast(const float* __restrict__ in,
                                               bf16_t* __restrict__ out,
                                               int R, int C) {
  __shared__ bf16_t tile[64][72];
  int c0 = blockIdx.x * 64, r0 = blockIdx.y * 64;
  int t = threadIdx.x;
  int r = t >> 2, cc = (t & 3) * 16;
  const float* src = in + (size_t)(r0 + r) * C + c0 + cc;
#pragma unroll
  for (int q = 0; q < 4; ++q) {
    float4 v = *(const float4*)(src + q * 4);
    tile[r][cc + q * 4 + 0] = (bf16_t)v.x;
    tile[r][cc + q * 4 + 1] = (bf16_t)v.y;
    tile[r][cc + q * 4 + 2] = (bf16_t)v.z;
    tile[r][cc + q * 4 + 3] = (bf16_t)v.w;
  }
  __syncthreads();
  int c = t >> 2, rr = (t & 3) * 16;
  bf16x8 o0, o1;
#pragma unroll
  for (int j = 0; j < 8; ++j) { o0[j] = tile[rr + j][c]; o1[j] = tile[rr + 8 + j][c]; }
  bf16_t* dst = out + (size_t)(c0 + c) * R + r0 + rr;
  *(bf16x8*)dst = o0;
  *(bf16x8*)(dst + 8) = o1;
}

// ---- fused QKV GEMM (2-phase dbuf): epilogue scatters to qh/kh/vT ----
// qh[bh][2048][64]; kh[bh][2048][64] scaled by log2(e)/8; vT[bh*64+d][2048].
__global__ __launch_bounds__(256) void k_gemm_qkv(const bf16_t* __restrict__ A,
                                                  const bf16_t* __restrict__ BT,
                                                  bf16_t* __restrict__ qh,
                                                  bf16_t* __restrict__ kh,
                                                  bf16_t* __restrict__ vT) {
  constexpr int K = 1024;
  // layout: [0,16K) = sA dbuf, [16K,32K) = sB dbuf; epilogue vtile overlays [0,36K)
  __shared__ alignas(16) char smem[36864];
  int tid = threadIdx.x;
  int wid = tid >> 6, lane = tid & 63;
  int cl = lane & 15, gp = lane >> 4;
  int nwg = gridDim.x * gridDim.y;
  int flat = blockIdx.y * gridDim.x + blockIdx.x;
  int cpx = nwg >> 3;
  int swzid = (flat & 7) * cpx + (flat >> 3);
  int brow = (swzid / gridDim.x) * 128, bcol = (swzid % gridDim.x) * 128;
  int wr = wid >> 1, wc = wid & 1;
  f32x4 acc[4][4];
#pragma unroll
  for (int i = 0; i < 4; ++i)
#pragma unroll
    for (int j = 0; j < 4; ++j) acc[i][j] = zero4();

  int srow = tid >> 2;
  int sk = (tid & 3) * 8;
  const bf16_t* gA = A + (size_t)(brow + srow) * K + sk;
  const bf16_t* gB = BT + (size_t)(bcol + srow) * K + sk;

  // prologue: stage tile 0 into buf 0
  {
    char* lA = smem + wid * 1024;
    char* lB = smem + 16384 + wid * 1024;
    GLOAD_LDS16(gA, lA);
    GLOAD_LDS16(gA + (size_t)64 * K, lA + 4096);
    GLOAD_LDS16(gB, lB);
    GLOAD_LDS16(gB + (size_t)64 * K, lB + 4096);
  }
  __syncthreads();

  int cur = 0;
  for (int k0 = 0; k0 < K; k0 += 32, cur ^= 1) {
    if (k0 + 32 < K) {                       // prefetch next K-tile into buf^1
      char* lA = smem + (cur ^ 1) * 8192 + wid * 1024;
      char* lB = smem + 16384 + (cur ^ 1) * 8192 + wid * 1024;
      GLOAD_LDS16(gA + k0 + 32, lA);
      GLOAD_LDS16(gA + (size_t)64 * K + k0 + 32, lA + 4096);
      GLOAD_LDS16(gB + k0 + 32, lB);
      GLOAD_LDS16(gB + (size_t)64 * K + k0 + 32, lB + 4096);
    }
    const bf16_t* bA = (const bf16_t*)(smem + cur * 8192);
    const bf16_t* bB = (const bf16_t*)(smem + 16384 + cur * 8192);
    bf16x8 af[4], bfr[4];
#pragma unroll
    for (int i = 0; i < 4; ++i)
      af[i] = *(const bf16x8*)&bA[(wr * 64 + i * 16 + cl) * 32 + gp * 8];
#pragma unroll
    for (int j = 0; j < 4; ++j)
      bfr[j] = *(const bf16x8*)&bB[(wc * 64 + j * 16 + cl) * 32 + gp * 8];
#pragma unroll
    for (int i = 0; i < 4; ++i)
#pragma unroll
      for (int j = 0; j < 4; ++j)
        acc[i][j] = MFMA16(af[i], bfr[j], acc[i][j]);
    __syncthreads();                         // drains prefetch vmcnt + LDS reads
  }

  // epilogue: this wave's 64-col span = exactly one head of one region
  int b_ = brow >> 11;                         // batch (2048 rows each)
  int t0 = (brow & 2047) + wr * 64;            // token offset of this wave
  int colbase = bcol + wc * 64;
  int region = colbase >> 10;                  // 0=Q 1=K 2=V
  int h_ = (colbase & 1023) >> 6;
  size_t bh_ = (size_t)(b_ * 16 + h_);
  bf16_t (*vt)[72] = (bf16_t(*)[72])(smem + wid * 9216);   // wave-private overlay

  if (region < 2) {
    // stage [token][d] then vector-store one 128B token-row per lane
    float sc = (region == 0) ? 1.0f : 0.18033688011f;   // log2(e)/8 for K
#pragma unroll
    for (int i = 0; i < 4; ++i)
#pragma unroll
      for (int j = 0; j < 4; ++j)
#pragma unroll
        for (int e = 0; e < 4; ++e)
          vt[i * 16 + gp * 4 + e][j * 16 + cl] = (bf16_t)(acc[i][j][e] * sc);
    bf16_t* dst0 = (region == 0 ? qh : kh) + (bh_ * 2048 + t0 + lane) * 64;
    const bf16_t* src = &vt[lane][0];
#pragma unroll
    for (int q = 0; q < 64; q += 8)
      *(bf16x8*)(dst0 + q) = *(const bf16x8*)(src + q);
  } else {
    // stage transposed [d][token] then vector-store one token-run per lane
#pragma unroll
    for (int i = 0; i < 4; ++i)
#pragma unroll
      for (int j = 0; j < 4; ++j)
#pragma unroll
        for (int e = 0; e < 4; ++e)
          vt[j * 16 + cl][i * 16 + gp * 4 + e] = (bf16_t)acc[i][j][e];
    const bf16_t* src = &vt[lane][0];
    bf16_t* dst = vT + (bh_ * 64 + lane) * 2048 + t0;
#pragma unroll
    for (int tt = 0; tt < 64; tt += 8)
      *(bf16x8*)(dst + tt) = *(const bf16x8*)(src + tt);
  }
}

// ------- proj GEMM (2-phase dbuf): C = A * BT^T + bias (fp32 out) -------
__global__ __launch_bounds__(256) void k_gemm_proj(const bf16_t* __restrict__ A,
                                                   const bf16_t* __restrict__ BT,
                                                   float* __restrict__ Cout,
                                                   const float* __restrict__ bias,
                                                   int M, int N, int K) {
  // layout: [0,16K) = sA dbuf, [16K,32K) = sB dbuf; epilogue ptile overlays [0,17.4K)
  __shared__ alignas(16) char smem[32768];
  int tid = threadIdx.x;
  int wid = tid >> 6, lane = tid & 63;
  int cl = lane & 15, gp = lane >> 4;
  int nwg = gridDim.x * gridDim.y;
  int flat = blockIdx.y * gridDim.x + blockIdx.x;
  int cpx = nwg >> 3;
  int swzid = (flat & 7) * cpx + (flat >> 3);
  int brow = (swzid / gridDim.x) * 128, bcol = (swzid % gridDim.x) * 128;
  int wr = wid >> 1, wc = wid & 1;
  f32x4 acc[4][4];
#pragma unroll
  for (int i = 0; i < 4; ++i)
#pragma unroll
    for (int j = 0; j < 4; ++j) acc[i][j] = zero4();

  int srow = tid >> 2;
  int sk = (tid & 3) * 8;
  const bf16_t* gA = A + (size_t)(brow + srow) * K + sk;
  const bf16_t* gB = BT + (size_t)(bcol + srow) * K + sk;

  {
    char* lA = smem + wid * 1024;
    char* lB = smem + 16384 + wid * 1024;
    GLOAD_LDS16(gA, lA);
    GLOAD_LDS16(gA + (size_t)64 * K, lA + 4096);
    GLOAD_LDS16(gB, lB);
    GLOAD_LDS16(gB + (size_t)64 * K, lB + 4096);
  }
  __syncthreads();

  int cur = 0;
  for (int k0 = 0; k0 < K; k0 += 32, cur ^= 1) {
    if (k0 + 32 < K) {
      char* lA = smem + (cur ^ 1) * 8192 + wid * 1024;
      char* lB = smem + 16384 + (cur ^ 1) * 8192 + wid * 1024;
      GLOAD_LDS16(gA + k0 + 32, lA);
      GLOAD_LDS16(gA + (size_t)64 * K + k0 + 32, lA + 4096);
      GLOAD_LDS16(gB + k0 + 32, lB);
      GLOAD_LDS16(gB + (size_t)64 * K + k0 + 32, lB + 4096);
    }
    const bf16_t* bA = (const bf16_t*)(smem + cur * 8192);
    const bf16_t* bB = (const bf16_t*)(smem + 16384 + cur * 8192);
    bf16x8 af[4], bfr[4];
#pragma unroll
    for (int i = 0; i < 4; ++i)
      af[i] = *(const bf16x8*)&bA[(wr * 64 + i * 16 + cl) * 32 + gp * 8];
#pragma unroll
    for (int j = 0; j < 4; ++j)
      bfr[j] = *(const bf16x8*)&bB[(wc * 64 + j * 16 + cl) * 32 + gp * 8];
#pragma unroll
    for (int i = 0; i < 4; ++i)
#pragma unroll
      for (int j = 0; j < 4; ++j)
        acc[i][j] = MFMA16(af[i], bfr[j], acc[i][j]);
    __syncthreads();
  }

  // epilogue: per i-chunk LDS repack -> float4 stores (bias hoisted)
  int r = lane & 15, q = lane >> 4;            // lane covers row r, col quarter q
  int colq = bcol + wc * 64 + q * 16;
  float4 bias4[4];
#pragma unroll
  for (int q2 = 0; q2 < 4; ++q2) bias4[q2] = *(const float4*)(bias + colq + q2 * 4);
  float (*pt)[68] = (float(*)[68])(smem + wid * 4352);     // wave-private overlay
#pragma unroll
  for (int i = 0; i < 4; ++i) {
#pragma unroll
    for (int j = 0; j < 4; ++j)
#pragma unroll
      for (int e = 0; e < 4; ++e)
        pt[gp * 4 + e][j * 16 + cl] = acc[i][j][e];
    asm volatile("" ::: "memory");             // order writes vs reads (same wave)
    float* dst = Cout + (size_t)(brow + wr * 64 + i * 16 + r) * N + colq;
#pragma unroll
    for (int q2 = 0; q2 < 4; ++q2) {
      float4 v = *(const float4*)&pt[r][q * 16 + q2 * 4];
      v.x += bias4[q2].x; v.y += bias4[q2].y; v.z += bias4[q2].z; v.w += bias4[q2].w;
      *(float4*)(dst + q2 * 4) = v;
    }
    asm volatile("" ::: "memory");             // reads done before next chunk writes
  }
}

// ---------------- attention v6 (exp2 domain, lsum via ones-MFMA) ----------------
static __device__ __forceinline__ float max3f(float a, float b, float c) {
  return fmaxf(fmaxf(a, b), c);                // fuses to v_max3_f32
}

static __device__ __forceinline__ void pass16(const char* __restrict__ bK,
                                              const char* __restrict__ bV,
                                              char* __restrict__ Pw,
                                              const bf16x8& qa, const bf16x8& qb,
                                              const bf16x8& ones8,
                                              f32x4 (&o)[4], f32x4& ol, float& mrun,
                                              int kv0, int qw, int swz, int cl, int gp) {
  f32x4 s[4];
  __builtin_amdgcn_s_setprio(1);
#pragma unroll
  for (int jj = 0; jj < 4; ++jj) {
    const char* base = bK + (jj * 16 + cl) * 128;
    bf16x8 k0 = *(const bf16x8*)(base + ((gp * 16) ^ swz));
    bf16x8 k1 = *(const bf16x8*)(base + ((64 + gp * 16) ^ swz));
    f32x4 a = zero4();
    a = MFMA16(k0, qa, a);
    a = MFMA16(k1, qb, a);
    s[jj] = a;
  }
  __builtin_amdgcn_s_setprio(0);

  if (kv0 + 63 > qw) {                        // only the diagonal tile masks
    int thr = qw + cl - kv0 - gp * 4;         // elem (jj,e) masked iff jj*16+e > thr
#pragma unroll
    for (int jj = 0; jj < 4; ++jj)
#pragma unroll
      for (int e = 0; e < 4; ++e)
        if (jj * 16 + e > thr) s[jj][e] = -1e30f;
  }
  float m1 = max3f(s[0][0], s[0][1], s[0][2]);
  float m2 = max3f(s[0][3], s[1][0], s[1][1]);
  float m3 = max3f(s[1][2], s[1][3], s[2][0]);
  float m4 = max3f(s[2][1], s[2][2], s[2][3]);
  float m5 = max3f(s[3][0], s[3][1], s[3][2]);
  float pm = fmaxf(max3f(max3f(m1, m2, m3), m4, m5), s[3][3]);
  pm = fmaxf(pm, __shfl_xor(pm, 16));
  pm = fmaxf(pm, __shfl_xor(pm, 32));
  float mnew = mrun;
  if (!__all(pm <= mnew + 11.5f)) {           // defer-max (T13), log2 domain
    float mold = mnew;
    mnew = fmaxf(mold, pm);
    float aa = exp2f(mold - mnew);
    mrun = mnew;
#pragma unroll
    for (int e = 0; e < 4; ++e) {
      float ae = __shfl(aa, gp * 4 + e);
      ol[e] *= ae;
#pragma unroll
      for (int c = 0; c < 4; ++c) o[c][e] *= ae;
    }
  }
#pragma unroll
  for (int jj = 0; jj < 4; ++jj) {
    bf16x4 pw;
#pragma unroll
    for (int e = 0; e < 4; ++e) pw[e] = (bf16_t)exp2f(s[jj][e] - mnew);
    *(bf16x4*)(Pw + cl * 128 + ((jj * 32 + gp * 8) ^ swz)) = pw;
  }

  asm volatile("" ::: "memory");              // P writes before P reads (same wave)
  bf16x8 pa0 = *(const bf16x8*)(Pw + cl * 128 + ((gp * 16) ^ swz));
  bf16x8 pa1 = *(const bf16x8*)(Pw + cl * 128 + ((64 + gp * 16) ^ swz));

  __builtin_amdgcn_s_setprio(1);
  ol = MFMA16(pa0, ones8, ol);                // lsum on the idle MFMA pipe
  ol = MFMA16(pa1, ones8, ol);
#pragma unroll
  for (int c = 0; c < 4; ++c) {
    const char* base = bV + (c * 16 + cl) * 128;
    bf16x8 v0 = *(const bf16x8*)(base + ((gp * 16) ^ swz));
    bf16x8 v1 = *(const bf16x8*)(base + ((64 + gp * 16) ^ swz));
    o[c] = MFMA16(pa0, v0, o[c]);
    o[c] = MFMA16(pa1, v1, o[c]);
  }
  __builtin_amdgcn_s_setprio(0);
  asm volatile("" ::: "memory");              // pa/v reads done before P rewrite
}

// ---- attention: QBLK=64, paired q-tiles (jL, 31-jL), 4 blocks/CU ----
__global__ __launch_bounds__(256, 4) void k_attn6(const bf16_t* __restrict__ qh,
                                                  const bf16_t* __restrict__ kh,
                                                  const bf16_t* __restrict__ vT,
                                                  bf16_t* __restrict__ out) {
  __shared__ alignas(16) char sK[2][8192];     // [64 kv][128B d], XOR-swizzled
  __shared__ alignas(16) char sV[2][8192];     // [64 d][128B kv], XOR-swizzled
  __shared__ alignas(16) char sP[4][2048];     // per wave: 16q x 128B P buffer

  int n = blockIdx.x;
  int bh = ((n & 7) << 3) | ((n >> 3) & 7);    // same head group -> same XCD
  int pr = n >> 6;                             // 0..15
  int jL = pr, jH = 31 - pr;                   // paired q-tiles: uniform work
  int b = bh >> 4;
  int tid = threadIdx.x, wid = tid >> 6, lane = tid & 63;
  int cl = lane & 15, gp = lane >> 4;

  int qwL = jL * 64 + wid * 16;
  int qwH = jH * 64 + wid * 16;

  // Q fragments (B-operand) from compact qh: col=cl(q), k(d)=gp*8+e
  bf16x8 qL0, qL1, qH0, qH1;
  {
    const bf16_t* p = qh + ((size_t)bh * 2048 + qwL + cl) * 64 + gp * 8;
    qL0 = *(const bf16x8*)p; qL1 = *(const bf16x8*)(p + 32);
    p = qh + ((size_t)bh * 2048 + qwH + cl) * 64 + gp * 8;
    qH0 = *(const bf16x8*)p; qH1 = *(const bf16x8*)(p + 32);
  }
  bf16x8 ones8;
#pragma unroll
  for (int e = 0; e < 8; ++e) ones8[e] = (bf16_t)1.0f;

  int srow = tid >> 3;
  int swzcb = ((tid & 7) * 16) ^ ((srow & 7) << 4);
  const bf16_t* gK = kh + ((size_t)bh * 2048 + srow) * 64 + (swzcb >> 1);
  const bf16_t* gV = vT + ((size_t)(bh * 64) + srow) * 2048 + (swzcb >> 1);

  f32x4 oL[4], oH[4], olL = zero4(), olH = zero4();
#pragma unroll
  for (int c = 0; c < 4; ++c) { oL[c] = zero4(); oH[c] = zero4(); }
  float mrunL = -1e30f, mrunH = -1e30f;

  int swz = (cl & 7) << 4;
  int nt = jH + 1;                             // KV64 tiles (H's causal extent)
  char* Pw = sP[wid];

  {
    char* lK = sK[0] + wid * 1024;
    char* lV = sV[0] + wid * 1024;
    GLOAD_LDS16(gK, lK);
    GLOAD_LDS16(gK + 32 * 64, lK + 4096);
    GLOAD_LDS16(gV, lV);
    GLOAD_LDS16(gV + (size_t)32 * 2048, lV + 4096);
  }
  asm volatile("s_waitcnt vmcnt(0)");
  __syncthreads();

  for (int t = 0; t < nt; ++t) {
    int cur = t & 1;
    int kv0 = t * 64;
    if (t + 1 < nt) {
      int kv1 = kv0 + 64;
      char* lK = sK[cur ^ 1] + wid * 1024;
      char* lV = sV[cur ^ 1] + wid * 1024;
      GLOAD_LDS16(gK + (size_t)kv1 * 64, lK);
      GLOAD_LDS16(gK + (size_t)(kv1 + 32) * 64, lK + 4096);
      GLOAD_LDS16(gV + kv1, lV);
      GLOAD_LDS16(gV + kv1 + (size_t)32 * 2048, lV + 4096);
    }
    const char* bK = sK[cur];
    const char* bV = sV[cur];

    if (t <= jL)
      pass16(bK, bV, Pw, qL0, qL1, ones8, oL, olL, mrunL, kv0, qwL, swz, cl, gp);
    pass16(bK, bV, Pw, qH0, qH1, ones8, oH, olH, mrunH, kv0, qwH, swz, cl, gp);

    asm volatile("s_waitcnt vmcnt(0)");
    __syncthreads();
  }

  // epilogue: lsum already in acc-row domain (ol[e] = row gp*4+e) -> no shuffles
#pragma unroll
  for (int e = 0; e < 4; ++e) {
    float iL = 1.0f / olL[e];
    float iH = 1.0f / olH[e];
    int rL = qwL + gp * 4 + e;
    int rH = qwH + gp * 4 + e;
    int h = bh & 15;
#pragma unroll
    for (int c = 0; c < 4; ++c) {
      int col = h * 64 + c * 16 + cl;
      out[(size_t)(b * 2048 + rL) * 1024 + col] = (bf16_t)(oL[c][e] * iL);
      out[(size_t)(b * 2048 + rH) * 1024 + col] = (bf16_t)(oH[c][e] * iH);
    }
  }
}

// ---------------------------------------------------------------------------
extern "C" void kernel_launch(void* const* d_in, const int* in_sizes, int n_in,
                              void* d_out, int out_size, void* d_ws, size_t ws_size,
                              hipStream_t stream) {
  const float* x      = (const float*)d_in[0];
  const float* w_qkv  = (const float*)d_in[1];
  const float* w_proj = (const float*)d_in[2];
  const float* b_proj = (const float*)d_in[3];
  float* outp = (float*)d_out;

  char* ws = (char*)d_ws;
  bf16_t* xb     = (bf16_t*)(ws);                    // 16 MiB
  bf16_t* wqkvT  = (bf16_t*)(ws + (16u << 20));      // 6 MiB
  bf16_t* wprojT = (bf16_t*)(ws + (22u << 20));      // 2 MiB
  bf16_t* qh     = (bf16_t*)(ws + (24u << 20));      // 16 MiB
  bf16_t* kh     = (bf16_t*)(ws + (40u << 20));      // 16 MiB
  bf16_t* vT     = (bf16_t*)(ws + (56u << 20));      // 16 MiB
  bf16_t* aout   = (bf16_t*)(ws + (72u << 20));      // 16 MiB

  k_cast<<<dim3(8192 * 1024 / (256 * 8)), 256, 0, stream>>>(x, xb);
  k_tcast<<<dim3(3072 / 64, 1024 / 64), 256, 0, stream>>>(w_qkv, wqkvT, 1024, 3072);
  k_tcast<<<dim3(1024 / 64, 1024 / 64), 256, 0, stream>>>(w_proj, wprojT, 1024, 1024);
  k_gemm_qkv<<<dim3(3072 / 128, 8192 / 128), 256, 0, stream>>>(xb, wqkvT, qh, kh, vT);
  k_attn6<<<dim3(1024), 256, 0, stream>>>(qh, kh, vT, aout);
  k_gemm_proj<<<dim3(1024 / 128, 8192 / 128), 256, 0, stream>>>(
      aout, wprojT, outp, b_proj, 8192, 1024, 1024);
}